// Round 1
// baseline (171.844 us; speedup 1.0000x reference)
//
#include <hip/hip_runtime.h>

// Bidirectional Chamfer loss:
//   cd1 = sum over shape points of min squared dist to skel points
//   cd2 = sum over skel points of min squared dist to shape points
//   out = (cd1 + cd2) * 1e-4
//
// Strategy: per-query min computed with target-dimension split for
// parallelism; partial mins merged via atomicMin on float bit patterns
// (valid: all d^2 >= 0, positive floats order like uints). Workspace
// holds one uint per query point (B*N + B*M = 40960 entries = 160 KB).

#define CHUNK 1024   // target points staged in LDS per block (16 KB as float4)

__global__ __launch_bounds__(256) void min_dist_kernel(
    const float* __restrict__ q,   // [B, nq, 3] queries
    const float* __restrict__ t,   // [B, mt, 3] targets
    unsigned int* __restrict__ ws, // [B*nq] running min (float bits)
    int nq, int mt)
{
    __shared__ float4 lds[CHUNK];

    const int b      = blockIdx.z;
    const int tid    = threadIdx.x;
    const int qi     = blockIdx.x * 256 + tid;     // query index within batch
    const int cstart = blockIdx.y * CHUNK;         // target chunk start

    // Stage this chunk of the target cloud into LDS (padded to float4).
    const float* tb = t + ((size_t)b * mt + cstart) * 3;
    #pragma unroll
    for (int p = tid; p < CHUNK; p += 256) {
        lds[p] = make_float4(tb[p * 3 + 0], tb[p * 3 + 1], tb[p * 3 + 2], 0.0f);
    }
    __syncthreads();

    // Load my query point.
    const float* qp = q + ((size_t)b * nq + qi) * 3;
    const float x = qp[0], y = qp[1], z = qp[2];

    float m = 3.4e38f;
    #pragma unroll 4
    for (int j = 0; j < CHUNK; ++j) {
        float4 tp = lds[j];            // broadcast read: no bank conflict
        float dx = x - tp.x;
        float dy = y - tp.y;
        float dz = z - tp.z;
        float d2 = dx * dx + dy * dy + dz * dz;
        m = fminf(m, d2);
    }

    atomicMin(&ws[(size_t)b * nq + qi], __float_as_uint(m));
}

__global__ __launch_bounds__(1024) void reduce_kernel(
    const unsigned int* __restrict__ ws, int n, float* __restrict__ out)
{
    float s = 0.0f;
    for (int i = threadIdx.x; i < n; i += 1024)
        s += __uint_as_float(ws[i]);

    // wave64 reduction
    #pragma unroll
    for (int off = 32; off > 0; off >>= 1)
        s += __shfl_down(s, off);

    __shared__ float wsum[16];
    const int lane = threadIdx.x & 63;
    const int w    = threadIdx.x >> 6;
    if (lane == 0) wsum[w] = s;
    __syncthreads();

    if (threadIdx.x == 0) {
        float tot = 0.0f;
        #pragma unroll
        for (int i = 0; i < 16; ++i) tot += wsum[i];
        out[0] = tot * 1.0e-4f;
    }
}

extern "C" void kernel_launch(void* const* d_in, const int* in_sizes, int n_in,
                              void* d_out, int out_size, void* d_ws, size_t ws_size,
                              hipStream_t stream) {
    const float* shape = (const float*)d_in[0];   // [4, 8192, 3]
    const float* skel  = (const float*)d_in[1];   // [4, 2048, 3]
    float* out         = (float*)d_out;           // scalar f32
    unsigned int* ws   = (unsigned int*)d_ws;

    const int B = 4, N = 8192, M = 2048;

    // Init all per-query mins to a huge positive float (0x7F7F7F7F ~ 3.39e38).
    hipMemsetAsync(d_ws, 0x7F, (size_t)(B * N + B * M) * sizeof(unsigned int), stream);

    // Direction 1: shape -> skel.  Grid: 32 query-blocks x 2 target-chunks x 4 batches.
    dim3 g1(N / 256, M / CHUNK, B);
    min_dist_kernel<<<g1, 256, 0, stream>>>(shape, skel, ws, N, M);

    // Direction 2: skel -> shape.  Grid: 8 query-blocks x 8 target-chunks x 4 batches.
    dim3 g2(M / 256, N / CHUNK, B);
    min_dist_kernel<<<g2, 256, 0, stream>>>(skel, shape, ws + (size_t)B * N, M, N);

    reduce_kernel<<<1, 1024, 0, stream>>>(ws, B * N + B * M, out);
}

// Round 2
// 45.620 us; speedup vs baseline: 3.7669x; 3.7669x over previous
//
#include <hip/hip_runtime.h>

// Bidirectional Chamfer loss, fused:
//   out = 1e-4 * ( sum_n min_m |shape[b,n]-skel[b,m]|^2
//                + sum_m min_n |skel[b,m]-shape[b,n]|^2 )
//
// One kernel handles BOTH directions (block-decoded) for full occupancy:
//   dir1: 8192 queries x 2048 targets per batch -> 32 qblocks x 8 chunks
//   dir2: 2048 queries x 8192 targets per batch -> 8 qblocks x 32 chunks
//   => 512 tiles/batch x 4 batches = 2048 blocks, 256 thr = 8 blocks/CU
//      = 32 waves/CU (100% occupancy budget at ~16-24 VGPR).
// Per-query partial mins merged with atomicMin on float bits (all d2 >= 0,
// positive floats order like uints). ws: 40960 uints (160 KB).

#define CHUNK 256   // targets staged in LDS per block (4 KB as float4)
#define QB    256   // queries per block (= blockDim.x)
#define BIGF  3.4e38f

__global__ __launch_bounds__(256) void chamfer_kernel(
    const float* __restrict__ shape,  // [4, 8192, 3]
    const float* __restrict__ skel,   // [4, 2048, 3]
    unsigned int* __restrict__ ws)    // [4*8192 + 4*2048]
{
    const int b   = blockIdx.y;
    const int tid = threadIdx.x;

    const float* q; const float* t; unsigned int* wbase;
    int nq, mt, qb, ch;
    int x = blockIdx.x;
    if (x < 256) {                    // dir1: shape -> skel
        q = shape; t = skel; nq = 8192; mt = 2048; wbase = ws;
        qb = x >> 3; ch = x & 7;      // 32 qblocks x 8 chunks
    } else {                          // dir2: skel -> shape
        x -= 256;
        q = skel; t = shape; nq = 2048; mt = 8192; wbase = ws + 4 * 8192;
        qb = x >> 5; ch = x & 31;     // 8 qblocks x 32 chunks
    }

    __shared__ float4 lds[CHUNK];

    // Stage chunk of targets (256 pts x 12 B, coalesced 12 B/lane).
    {
        const float* tb = t + ((size_t)b * mt + ch * CHUNK) * 3;
        lds[tid] = make_float4(tb[tid * 3 + 0], tb[tid * 3 + 1],
                               tb[tid * 3 + 2], 0.0f);
    }
    __syncthreads();

    // My query point.
    const int qi = qb * QB + tid;
    const float* qp = q + ((size_t)b * nq + qi) * 3;
    const float xq = qp[0], yq = qp[1], zq = qp[2];

    // 4 independent min chains; 4-wide unroll over targets.
    float m0 = BIGF, m1 = BIGF, m2 = BIGF, m3 = BIGF;
    #pragma unroll 4
    for (int j = 0; j < CHUNK; j += 4) {
        float4 t0 = lds[j + 0];       // broadcast reads: conflict-free
        float4 t1 = lds[j + 1];
        float4 t2 = lds[j + 2];
        float4 t3 = lds[j + 3];
        float dx, dy, dz;
        dx = xq - t0.x; dy = yq - t0.y; dz = zq - t0.z;
        m0 = fminf(m0, dx * dx + dy * dy + dz * dz);
        dx = xq - t1.x; dy = yq - t1.y; dz = zq - t1.z;
        m1 = fminf(m1, dx * dx + dy * dy + dz * dz);
        dx = xq - t2.x; dy = yq - t2.y; dz = zq - t2.z;
        m2 = fminf(m2, dx * dx + dy * dy + dz * dz);
        dx = xq - t3.x; dy = yq - t3.y; dz = zq - t3.z;
        m3 = fminf(m3, dx * dx + dy * dy + dz * dz);
    }
    float m = fminf(fminf(m0, m1), fminf(m2, m3));

    atomicMin(&wbase[(size_t)b * nq + qi], __float_as_uint(m));
}

__global__ __launch_bounds__(1024) void reduce_kernel(
    const unsigned int* __restrict__ ws, int n4, float* __restrict__ out)
{
    const uint4* w4 = (const uint4*)ws;
    float s = 0.0f;
    for (int i = threadIdx.x; i < n4; i += 1024) {
        uint4 v = w4[i];
        s += __uint_as_float(v.x) + __uint_as_float(v.y)
           + __uint_as_float(v.z) + __uint_as_float(v.w);
    }

    #pragma unroll
    for (int off = 32; off > 0; off >>= 1)
        s += __shfl_down(s, off);

    __shared__ float wsum[16];
    const int lane = threadIdx.x & 63;
    const int w    = threadIdx.x >> 6;
    if (lane == 0) wsum[w] = s;
    __syncthreads();

    if (threadIdx.x == 0) {
        float tot = 0.0f;
        #pragma unroll
        for (int i = 0; i < 16; ++i) tot += wsum[i];
        out[0] = tot * 1.0e-4f;
    }
}

extern "C" void kernel_launch(void* const* d_in, const int* in_sizes, int n_in,
                              void* d_out, int out_size, void* d_ws, size_t ws_size,
                              hipStream_t stream) {
    const float* shape = (const float*)d_in[0];   // [4, 8192, 3]
    const float* skel  = (const float*)d_in[1];   // [4, 2048, 3]
    float* out         = (float*)d_out;           // scalar f32
    unsigned int* ws   = (unsigned int*)d_ws;

    const int B = 4, N = 8192, M = 2048;
    const int NW = B * N + B * M;                 // 40960

    // Init per-query mins to huge positive float (0x7F7F7F7F ~ 3.39e38).
    hipMemsetAsync(d_ws, 0x7F, (size_t)NW * sizeof(unsigned int), stream);

    // 512 tiles/batch (256 dir1 + 256 dir2) x 4 batches.
    chamfer_kernel<<<dim3(512, B), 256, 0, stream>>>(shape, skel, ws);

    reduce_kernel<<<1, 1024, 0, stream>>>(ws, NW / 4, out);
}

// Round 3
// 45.513 us; speedup vs baseline: 3.7757x; 1.0023x over previous
//
#include <hip/hip_runtime.h>

// Bidirectional Chamfer loss, fused:
//   out = 1e-4 * ( sum_n min_m |shape[b,n]-skel[b,m]|^2
//                + sum_m min_n |skel[b,m]-shape[b,n]|^2 )
//
// R3 change: the hipMemsetAsync(160 KB) used to init the atomicMin
// workspace ran as __amd_rocclr_fillBufferAligned at ~40 us (~88% of
// total). Replaced with a one-store-per-thread init kernel.

#define CHUNK 256   // targets staged in LDS per block (4 KB as float4)
#define QB    256   // queries per block (= blockDim.x)
#define BIGF  3.4e38f
#define NWORK (4 * 8192 + 4 * 2048)   // 40960 per-query min slots

__global__ __launch_bounds__(1024) void init_ws_kernel(unsigned int* __restrict__ ws)
{
    const int i = blockIdx.x * 1024 + threadIdx.x;
    if (i < NWORK) ws[i] = 0x7F7F7F7Fu;   // ~3.39e38 as float bits
}

__global__ __launch_bounds__(256) void chamfer_kernel(
    const float* __restrict__ shape,  // [4, 8192, 3]
    const float* __restrict__ skel,   // [4, 2048, 3]
    unsigned int* __restrict__ ws)    // [NWORK]
{
    const int b   = blockIdx.y;
    const int tid = threadIdx.x;

    const float* q; const float* t; unsigned int* wbase;
    int nq, mt, qb, ch;
    int x = blockIdx.x;
    if (x < 256) {                    // dir1: shape -> skel
        q = shape; t = skel; nq = 8192; mt = 2048; wbase = ws;
        qb = x >> 3; ch = x & 7;      // 32 qblocks x 8 chunks
    } else {                          // dir2: skel -> shape
        x -= 256;
        q = skel; t = shape; nq = 2048; mt = 8192; wbase = ws + 4 * 8192;
        qb = x >> 5; ch = x & 31;     // 8 qblocks x 32 chunks
    }

    __shared__ float4 lds[CHUNK];

    // Stage chunk of targets (256 pts x 12 B, coalesced 12 B/lane).
    {
        const float* tb = t + ((size_t)b * mt + ch * CHUNK) * 3;
        lds[tid] = make_float4(tb[tid * 3 + 0], tb[tid * 3 + 1],
                               tb[tid * 3 + 2], 0.0f);
    }
    __syncthreads();

    // My query point.
    const int qi = qb * QB + tid;
    const float* qp = q + ((size_t)b * nq + qi) * 3;
    const float xq = qp[0], yq = qp[1], zq = qp[2];

    // 4 independent min chains; 4-wide unroll over targets.
    float m0 = BIGF, m1 = BIGF, m2 = BIGF, m3 = BIGF;
    #pragma unroll 4
    for (int j = 0; j < CHUNK; j += 4) {
        float4 t0 = lds[j + 0];       // broadcast reads: conflict-free
        float4 t1 = lds[j + 1];
        float4 t2 = lds[j + 2];
        float4 t3 = lds[j + 3];
        float dx, dy, dz;
        dx = xq - t0.x; dy = yq - t0.y; dz = zq - t0.z;
        m0 = fminf(m0, dx * dx + dy * dy + dz * dz);
        dx = xq - t1.x; dy = yq - t1.y; dz = zq - t1.z;
        m1 = fminf(m1, dx * dx + dy * dy + dz * dz);
        dx = xq - t2.x; dy = yq - t2.y; dz = zq - t2.z;
        m2 = fminf(m2, dx * dx + dy * dy + dz * dz);
        dx = xq - t3.x; dy = yq - t3.y; dz = zq - t3.z;
        m3 = fminf(m3, dx * dx + dy * dy + dz * dz);
    }
    float m = fminf(fminf(m0, m1), fminf(m2, m3));

    atomicMin(&wbase[(size_t)b * nq + qi], __float_as_uint(m));
}

__global__ __launch_bounds__(1024) void reduce_kernel(
    const unsigned int* __restrict__ ws, int n4, float* __restrict__ out)
{
    const uint4* w4 = (const uint4*)ws;
    float s = 0.0f;
    for (int i = threadIdx.x; i < n4; i += 1024) {
        uint4 v = w4[i];
        s += __uint_as_float(v.x) + __uint_as_float(v.y)
           + __uint_as_float(v.z) + __uint_as_float(v.w);
    }

    #pragma unroll
    for (int off = 32; off > 0; off >>= 1)
        s += __shfl_down(s, off);

    __shared__ float wsum[16];
    const int lane = threadIdx.x & 63;
    const int w    = threadIdx.x >> 6;
    if (lane == 0) wsum[w] = s;
    __syncthreads();

    if (threadIdx.x == 0) {
        float tot = 0.0f;
        #pragma unroll
        for (int i = 0; i < 16; ++i) tot += wsum[i];
        out[0] = tot * 1.0e-4f;
    }
}

extern "C" void kernel_launch(void* const* d_in, const int* in_sizes, int n_in,
                              void* d_out, int out_size, void* d_ws, size_t ws_size,
                              hipStream_t stream) {
    const float* shape = (const float*)d_in[0];   // [4, 8192, 3]
    const float* skel  = (const float*)d_in[1];   // [4, 2048, 3]
    float* out         = (float*)d_out;           // scalar f32
    unsigned int* ws   = (unsigned int*)d_ws;

    // Init per-query mins to huge positive float (replaces slow runtime fill).
    init_ws_kernel<<<(NWORK + 1023) / 1024, 1024, 0, stream>>>(ws);

    // 512 tiles/batch (256 dir1 + 256 dir2) x 4 batches = 2048 blocks.
    chamfer_kernel<<<dim3(512, 4), 256, 0, stream>>>(shape, skel, ws);

    reduce_kernel<<<1, 1024, 0, stream>>>(ws, NWORK / 4, out);
}

// Round 4
// 38.205 us; speedup vs baseline: 4.4979x; 1.1913x over previous
//
#include <hip/hip_runtime.h>

// Bidirectional Chamfer loss, fused:
//   out = 1e-4 * ( sum_n min_m |shape[b,n]-skel[b,m]|^2
//                + sum_m min_n |skel[b,m]-shape[b,n]|^2 )
//
// R4: register tiling. R3's kernel was LDS-issue-bound: one broadcast
// ds_read_b128 per 7 VALU ops => 8192 LDS instrs/CU x ~12cyc ~= 41 us.
// Now each thread keeps Q=8 query points in VGPRs, so one LDS read feeds
// 56 VALU ops; LDS issue drops 8x and the kernel is VALU-bound (~12 us
// floor = 134M pairs x 7 lane-ops / 78.6T lane-ops/s).

#define CHUNK 128    // targets staged in LDS per block (2 KB as float4)
#define QPT   8      // query points per thread (in VGPRs)
#define BIGF  3.4e38f
#define NWORK (4 * 8192 + 4 * 2048)   // 40960 per-query min slots

__global__ __launch_bounds__(1024) void init_ws_kernel(unsigned int* __restrict__ ws)
{
    const int i = blockIdx.x * 1024 + threadIdx.x;
    if (i < NWORK) ws[i] = 0x7F7F7F7Fu;   // ~3.39e38 as float bits
}

// Block covers 2048 queries (256 thr x 8) x CHUNK targets.
// dir1: 8192q x 2048t => 4 qblocks x 16 chunks = 64 tiles/batch
// dir2: 2048q x 8192t => 1 qblock  x 64 chunks = 64 tiles/batch
// grid = (128, 4) = 512 blocks = 2 blocks/CU = 2 waves/SIMD.
__global__ __launch_bounds__(256) void chamfer_kernel(
    const float* __restrict__ shape,  // [4, 8192, 3]
    const float* __restrict__ skel,   // [4, 2048, 3]
    unsigned int* __restrict__ ws)    // [NWORK]
{
    const int b   = blockIdx.y;
    const int tid = threadIdx.x;

    const float* q; const float* t; unsigned int* wbase;
    int nq, mt, qb, ch;
    int x = blockIdx.x;
    if (x < 64) {                     // dir1: shape -> skel
        q = shape; t = skel; nq = 8192; mt = 2048; wbase = ws;
        qb = x >> 4; ch = x & 15;     // 4 qblocks x 16 chunks
    } else {                          // dir2: skel -> shape
        x -= 64;
        q = skel; t = shape; nq = 2048; mt = 8192; wbase = ws + 4 * 8192;
        qb = 0;  ch = x;              // 1 qblock x 64 chunks
    }

    __shared__ float4 lds[CHUNK];

    // Stage chunk of targets (CHUNK pts x 12 B).
    if (tid < CHUNK) {
        const float* tb = t + ((size_t)b * mt + ch * CHUNK) * 3;
        lds[tid] = make_float4(tb[tid * 3 + 0], tb[tid * 3 + 1],
                               tb[tid * 3 + 2], 0.0f);
    }

    // Load my 8 query points (strided by 256 points for coalescing).
    const int q0 = qb * 2048 + tid;       // queries q0 + k*256
    const float* qp = q + ((size_t)b * nq + q0) * 3;
    float qx[QPT], qy[QPT], qz[QPT], mn[QPT];
    #pragma unroll
    for (int k = 0; k < QPT; ++k) {
        qx[k] = qp[k * 768 + 0];          // 768 = 256 pts * 3 floats
        qy[k] = qp[k * 768 + 1];
        qz[k] = qp[k * 768 + 2];
        mn[k] = BIGF;
    }

    __syncthreads();

    // One broadcast LDS read feeds QPT independent distance+min chains.
    #pragma unroll 2
    for (int j = 0; j < CHUNK; ++j) {
        float4 tp = lds[j];               // broadcast: conflict-free
        #pragma unroll
        for (int k = 0; k < QPT; ++k) {
            float dx = qx[k] - tp.x;
            float dy = qy[k] - tp.y;
            float dz = qz[k] - tp.z;
            mn[k] = fminf(mn[k], dx * dx + dy * dy + dz * dz);
        }
    }

    #pragma unroll
    for (int k = 0; k < QPT; ++k)
        atomicMin(&wbase[(size_t)b * nq + q0 + k * 256], __float_as_uint(mn[k]));
}

__global__ __launch_bounds__(1024) void reduce_kernel(
    const unsigned int* __restrict__ ws, int n4, float* __restrict__ out)
{
    const uint4* w4 = (const uint4*)ws;
    float s = 0.0f;
    for (int i = threadIdx.x; i < n4; i += 1024) {
        uint4 v = w4[i];
        s += __uint_as_float(v.x) + __uint_as_float(v.y)
           + __uint_as_float(v.z) + __uint_as_float(v.w);
    }

    #pragma unroll
    for (int off = 32; off > 0; off >>= 1)
        s += __shfl_down(s, off);

    __shared__ float wsum[16];
    const int lane = threadIdx.x & 63;
    const int w    = threadIdx.x >> 6;
    if (lane == 0) wsum[w] = s;
    __syncthreads();

    if (threadIdx.x == 0) {
        float tot = 0.0f;
        #pragma unroll
        for (int i = 0; i < 16; ++i) tot += wsum[i];
        out[0] = tot * 1.0e-4f;
    }
}

extern "C" void kernel_launch(void* const* d_in, const int* in_sizes, int n_in,
                              void* d_out, int out_size, void* d_ws, size_t ws_size,
                              hipStream_t stream) {
    const float* shape = (const float*)d_in[0];   // [4, 8192, 3]
    const float* skel  = (const float*)d_in[1];   // [4, 2048, 3]
    float* out         = (float*)d_out;           // scalar f32
    unsigned int* ws   = (unsigned int*)d_ws;

    init_ws_kernel<<<(NWORK + 1023) / 1024, 1024, 0, stream>>>(ws);

    // 128 tiles/batch (64 dir1 + 64 dir2) x 4 batches = 512 blocks.
    chamfer_kernel<<<dim3(128, 4), 256, 0, stream>>>(shape, skel, ws);

    reduce_kernel<<<1, 1024, 0, stream>>>(ws, NWORK / 4, out);
}

// Round 5
// 31.563 us; speedup vs baseline: 5.4445x; 1.2105x over previous
//
#include <hip/hip_runtime.h>

// Bidirectional Chamfer loss, fused:
//   out = 1e-4 * ( sum_n min_m |shape[b,n]-skel[b,m]|^2
//                + sum_m min_n |skel[b,m]-shape[b,n]|^2 )
//
// R5:
//  - 4 VALU ops/pair (was 7): d2 = qsq + (tsq - 2 q.t); stage tsq in LDS .w,
//    keep -2q per query in VGPRs; inner = 3 chained FMA + 1 min. qsq added
//    once per query in the epilogue; clamp >=0 commutes with min, done in
//    the reduce. VALU floor ~6.9 us.
//  - atomic-free: each (query, chunk) partial min goes to its own slot
//    (2.1M floats, written exactly once -> no init kernel, no contention).
//  - CHUNK=64 -> 1024 blocks = 4 blocks/CU = 4 waves/SIMD.
// Pipeline: chamfer -> reduce (min over chunks, clamp, block sum) ->
// final (deterministic sum of 160 block partials).

#define CHUNK  64     // targets per block tile (1 KB in LDS)
#define QPT    8      // query points per thread
#define BIGF   3.4e38f

// Partial layout in ws (floats):
//  dir1: [b][ch][q] : 4 x 32 x 8192 = 1,048,576
//  dir2: [b][ch][q] : 4 x 128 x 2048 = 1,048,576  (offset P2_OFF)
//  psum: 160 block partial sums                    (offset PSUM_OFF)
#define P2_OFF   1048576
#define PSUM_OFF 2097152
#define RBLOCKS  160

__global__ __launch_bounds__(256) void chamfer_kernel(
    const float* __restrict__ shape,  // [4, 8192, 3]
    const float* __restrict__ skel,   // [4, 2048, 3]
    float* __restrict__ pw)           // partial mins
{
    const int b   = blockIdx.y;
    const int tid = threadIdx.x;

    // Tile decode: 256 tiles/batch = 128 dir1 (4 qb x 32 ch) + 128 dir2 (1 x 128 ch).
    const float* q; const float* t; float* pbase;
    int nq, mt, qb, ch;
    int x = blockIdx.x;
    if (x < 128) {                    // dir1: shape -> skel
        q = shape; t = skel; nq = 8192; mt = 2048;
        qb = x >> 5; ch = x & 31;
        pbase = pw + ((size_t)b * 32 + ch) * 8192;
    } else {                          // dir2: skel -> shape
        x -= 128;
        q = skel; t = shape; nq = 2048; mt = 8192;
        qb = 0; ch = x;
        pbase = pw + P2_OFF + ((size_t)b * 128 + ch) * 2048;
    }

    __shared__ float4 lds[CHUNK];

    // Stage CHUNK targets as (x, y, z, |t|^2).
    if (tid < CHUNK) {
        const float* tb = t + ((size_t)b * mt + ch * CHUNK) * 3;
        float tx = tb[tid * 3 + 0], ty = tb[tid * 3 + 1], tz = tb[tid * 3 + 2];
        lds[tid] = make_float4(tx, ty, tz, tx * tx + ty * ty + tz * tz);
    }

    // Load my QPT query points; precompute -2q and |q|^2.
    const int q0 = qb * 2048 + tid;               // queries q0 + k*256
    const float* qp = q + ((size_t)b * nq + q0) * 3;
    float nqx[QPT], nqy[QPT], nqz[QPT], qsq[QPT], mn[QPT];
    #pragma unroll
    for (int k = 0; k < QPT; ++k) {
        float xq = qp[k * 768 + 0];               // 768 = 256 pts * 3
        float yq = qp[k * 768 + 1];
        float zq = qp[k * 768 + 2];
        nqx[k] = -2.0f * xq; nqy[k] = -2.0f * yq; nqz[k] = -2.0f * zq;
        qsq[k] = xq * xq + yq * yq + zq * zq;
        mn[k]  = BIGF;
    }

    __syncthreads();

    // 4 VALU ops per (query, target) pair: 3 FMA + 1 min.
    #pragma unroll 4
    for (int j = 0; j < CHUNK; ++j) {
        float4 tp = lds[j];                       // broadcast: conflict-free
        #pragma unroll
        for (int k = 0; k < QPT; ++k) {
            float e = fmaf(nqx[k], tp.x,
                      fmaf(nqy[k], tp.y,
                      fmaf(nqz[k], tp.z, tp.w)));
            mn[k] = fminf(mn[k], e);
        }
    }

    // One plain store per (query, chunk) partial — coalesced, no atomics.
    #pragma unroll
    for (int k = 0; k < QPT; ++k)
        pbase[q0 + k * 256] = qsq[k] + mn[k];
}

// Per query: min over chunk partials, clamp, then per-block sum.
__global__ __launch_bounds__(256) void reduce_kernel(
    const float* __restrict__ pw, float* __restrict__ psum)
{
    const int blk = blockIdx.x, tid = threadIdx.x;
    float s;
    if (blk < 128) {                              // dir1: 32768 queries, 32 chunks
        const int qg = blk * 256 + tid;
        const int b = qg >> 13, ql = qg & 8191;
        const float* p = pw + (size_t)b * 32 * 8192 + ql;
        float m0 = BIGF, m1 = BIGF, m2 = BIGF, m3 = BIGF;
        #pragma unroll
        for (int ch = 0; ch < 32; ch += 4) {      // coalesced per step
            m0 = fminf(m0, p[(ch + 0) * 8192]);
            m1 = fminf(m1, p[(ch + 1) * 8192]);
            m2 = fminf(m2, p[(ch + 2) * 8192]);
            m3 = fminf(m3, p[(ch + 3) * 8192]);
        }
        s = fmaxf(fminf(fminf(m0, m1), fminf(m2, m3)), 0.0f);
    } else {                                      // dir2: 8192 queries, 128 chunks
        const int qg = (blk - 128) * 256 + tid;
        const int b = qg >> 11, ql = qg & 2047;
        const float* p = pw + P2_OFF + (size_t)b * 128 * 2048 + ql;
        float m0 = BIGF, m1 = BIGF, m2 = BIGF, m3 = BIGF;
        #pragma unroll 8
        for (int ch = 0; ch < 128; ch += 4) {
            m0 = fminf(m0, p[(ch + 0) * 2048]);
            m1 = fminf(m1, p[(ch + 1) * 2048]);
            m2 = fminf(m2, p[(ch + 2) * 2048]);
            m3 = fminf(m3, p[(ch + 3) * 2048]);
        }
        s = fmaxf(fminf(fminf(m0, m1), fminf(m2, m3)), 0.0f);
    }

    #pragma unroll
    for (int off = 32; off > 0; off >>= 1)
        s += __shfl_down(s, off);

    __shared__ float wsum[4];
    const int lane = tid & 63, w = tid >> 6;
    if (lane == 0) wsum[w] = s;
    __syncthreads();
    if (tid == 0) psum[blk] = (wsum[0] + wsum[1]) + (wsum[2] + wsum[3]);
}

__global__ __launch_bounds__(64) void final_kernel(
    const float* __restrict__ psum, float* __restrict__ out)
{
    float s = 0.0f;
    for (int i = threadIdx.x; i < RBLOCKS; i += 64)
        s += psum[i];
    #pragma unroll
    for (int off = 32; off > 0; off >>= 1)
        s += __shfl_down(s, off);
    if (threadIdx.x == 0) out[0] = s * 1.0e-4f;
}

extern "C" void kernel_launch(void* const* d_in, const int* in_sizes, int n_in,
                              void* d_out, int out_size, void* d_ws, size_t ws_size,
                              hipStream_t stream) {
    const float* shape = (const float*)d_in[0];   // [4, 8192, 3]
    const float* skel  = (const float*)d_in[1];   // [4, 2048, 3]
    float* out         = (float*)d_out;           // scalar f32
    float* pw          = (float*)d_ws;

    // 256 tiles/batch x 4 batches = 1024 blocks (4/CU, 4 waves/SIMD).
    chamfer_kernel<<<dim3(256, 4), 256, 0, stream>>>(shape, skel, pw);

    reduce_kernel<<<RBLOCKS, 256, 0, stream>>>(pw, pw + PSUM_OFF);

    final_kernel<<<1, 64, 0, stream>>>(pw + PSUM_OFF, out);
}